// Round 7
// baseline (338.277 us; speedup 1.0000x reference)
//
#include <hip/hip_runtime.h>
#include <cstdint>
#include <cstddef>

// GAT forward on MI355X — CSR-gather formulation (no f32 atomics).
// Round 7: linear reverted to LDS-W + VALU, with x read as wave-uniform
// BROADCAST float4 global loads (no x staging, no SMEM chain — round 6's
// scalar-load experiment regressed via occupancy collapse). One 16-row tile
// per block, grid = N/16. Gather/fill/CSR unchanged from round 6.

// ---------------- Kernel 1: linear + logits ----------------
// Block = 256 thr (4 waves). Wave wi computes rows nb+wi*4..+3, lane = col.
// x rows are wave-uniform -> broadcast float4 loads (1 fetch/instr, L1).
__global__ __launch_bounds__(256) void gat_linear(
    const float* __restrict__ x, const float* __restrict__ W,
    const float* __restrict__ att_src, const float* __restrict__ att_dst,
    float* __restrict__ h, float* __restrict__ a_src, float* __restrict__ a_dst,
    int N)
{
    __shared__ float Wl[128 * 64];   // 32 KB
    const int tid  = threadIdx.x;
    const int lane = tid & 63;
    const int wi   = tid >> 6;

    for (int i = tid; i < 2048; i += 256)
        reinterpret_cast<float4*>(Wl)[i] = reinterpret_cast<const float4*>(W)[i];
    const float atts = att_src[lane];
    const float attd = att_dst[lane];
    __syncthreads();

    const int r0 = blockIdx.x * 16 + wi * 4;
    if (r0 >= N) return;
    const float* x0 = x + (size_t)r0 * 128;

    float acc0 = 0.f, acc1 = 0.f, acc2 = 0.f, acc3 = 0.f;
    if (r0 + 3 < N) {
        #pragma unroll 2
        for (int k4 = 0; k4 < 32; ++k4) {
            const int kb = k4 * 4;
            const float4 xa = *reinterpret_cast<const float4*>(x0 + 0 * 128 + kb);
            const float4 xb = *reinterpret_cast<const float4*>(x0 + 1 * 128 + kb);
            const float4 xc = *reinterpret_cast<const float4*>(x0 + 2 * 128 + kb);
            const float4 xd = *reinterpret_cast<const float4*>(x0 + 3 * 128 + kb);
            const float wa = Wl[(kb + 0) * 64 + lane];
            const float wb = Wl[(kb + 1) * 64 + lane];
            const float wc = Wl[(kb + 2) * 64 + lane];
            const float wd = Wl[(kb + 3) * 64 + lane];
            acc0 += xa.x * wa + xa.y * wb + xa.z * wc + xa.w * wd;
            acc1 += xb.x * wa + xb.y * wb + xb.z * wc + xb.w * wd;
            acc2 += xc.x * wa + xc.y * wb + xc.z * wc + xc.w * wd;
            acc3 += xd.x * wa + xd.y * wb + xd.z * wc + xd.w * wd;
        }
    } else {
        // tail tile (not hit at N=100000; generic safety)
        for (int k = 0; k < 128; ++k) {
            const float wv = Wl[k * 64 + lane];
            if (r0 + 0 < N) acc0 += x0[0 * 128 + k] * wv;
            if (r0 + 1 < N) acc1 += x0[1 * 128 + k] * wv;
            if (r0 + 2 < N) acc2 += x0[2 * 128 + k] * wv;
            if (r0 + 3 < N) acc3 += x0[3 * 128 + k] * wv;
        }
    }

    float accs[4] = {acc0, acc1, acc2, acc3};
    #pragma unroll
    for (int j = 0; j < 4; ++j) {
        const int node = r0 + j;
        if (node < N) {
            h[(size_t)node * 64 + lane] = accs[j];
            float vs = accs[j] * atts;
            float vd = accs[j] * attd;
            vs += __shfl_xor(vs, 1, 64); vd += __shfl_xor(vd, 1, 64);
            vs += __shfl_xor(vs, 2, 64); vd += __shfl_xor(vd, 2, 64);
            vs += __shfl_xor(vs, 4, 64); vd += __shfl_xor(vd, 4, 64);
            if ((lane & 7) == 0) {
                a_src[node * 8 + (lane >> 3)] = vs;
                a_dst[node * 8 + (lane >> 3)] = vd;
            }
        }
    }
}

// ---------------- CSR build ----------------
__global__ __launch_bounds__(256) void gat_hist(
    const int* __restrict__ e_dst, int* __restrict__ deg, int E)
{
    int i = blockIdx.x * 256 + threadIdx.x;
    int b = i * 4;
    if (b + 3 < E) {
        int4 d = *reinterpret_cast<const int4*>(e_dst + b);
        atomicAdd(&deg[d.x], 1);
        atomicAdd(&deg[d.y], 1);
        atomicAdd(&deg[d.z], 1);
        atomicAdd(&deg[d.w], 1);
    } else {
        for (int k = b; k < E; ++k) atomicAdd(&deg[e_dst[k]], 1);
    }
}

// Per-chunk (1024 elems) exclusive scan; chunkSum[b] = chunk total.
__global__ __launch_bounds__(256) void gat_scan_chunks(
    const int* __restrict__ deg, int* __restrict__ off,
    int* __restrict__ chunkSum, int N)
{
    __shared__ int lds[256];
    const int t = threadIdx.x;
    const int base = blockIdx.x * 1024 + t * 4;
    int v0 = 0, v1 = 0, v2 = 0, v3 = 0;
    if (base + 0 < N) v0 = deg[base + 0];
    if (base + 1 < N) v1 = deg[base + 1];
    if (base + 2 < N) v2 = deg[base + 2];
    if (base + 3 < N) v3 = deg[base + 3];
    int s = v0 + v1 + v2 + v3;
    lds[t] = s;
    __syncthreads();
    #pragma unroll
    for (int d = 1; d < 256; d <<= 1) {
        int add = (t >= d) ? lds[t - d] : 0;
        __syncthreads();
        lds[t] += add;
        __syncthreads();
    }
    if (t == 255) chunkSum[blockIdx.x] = lds[255];
    int p = lds[t] - s;  // exclusive within chunk
    if (base + 0 < N) off[base + 0] = p; p += v0;
    if (base + 1 < N) off[base + 1] = p; p += v1;
    if (base + 2 < N) off[base + 2] = p; p += v2;
    if (base + 3 < N) off[base + 3] = p;
}

// Exclusive scan of chunk sums (nChunks <= 128) in one 128-thread block.
__global__ __launch_bounds__(128) void gat_scan_tops(
    const int* __restrict__ chunkSum, int* __restrict__ chunkBase,
    int* __restrict__ off, int nChunks, int N)
{
    __shared__ int lds[128];
    const int t = threadIdx.x;
    if (nChunks > 128) {               // safety fallback (not hit at N=100k)
        if (t == 0) {
            int run = 0;
            for (int i = 0; i < nChunks; ++i) { chunkBase[i] = run; run += chunkSum[i]; }
            off[N] = run;
        }
        return;
    }
    int v = (t < nChunks) ? chunkSum[t] : 0;
    lds[t] = v;
    __syncthreads();
    #pragma unroll
    for (int d = 1; d < 128; d <<= 1) {
        int add = (t >= d) ? lds[t - d] : 0;
        __syncthreads();
        lds[t] += add;
        __syncthreads();
    }
    if (t < nChunks) chunkBase[t] = lds[t] - v;
    if (t == nChunks - 1) off[N] = lds[t];
}

__global__ __launch_bounds__(256) void gat_add_base(
    int* __restrict__ off, int* __restrict__ cursor,
    const int* __restrict__ chunkBase, int N)
{
    int i = blockIdx.x * 256 + threadIdx.x;
    if (i < N) {
        int v = off[i] + chunkBase[i >> 10];
        off[i] = v;
        cursor[i] = v;
    }
}

// dst-range-partitioned fill (see round 5 notes).
__global__ __launch_bounds__(256) void gat_fill(
    const int* __restrict__ e_src, const int* __restrict__ e_dst,
    int* __restrict__ cursor, int* __restrict__ esrc, int E, int N)
{
    const int range = blockIdx.x & 7;
    const int chunk = blockIdx.x >> 3;
    const int lo = (int)(((long long)N * range) >> 3);
    const int hi = (int)(((long long)N * (range + 1)) >> 3);

    const int b = chunk * 1024 + threadIdx.x * 4;
    if (b + 3 < E) {
        int4 sv = *reinterpret_cast<const int4*>(e_src + b);
        int4 dv = *reinterpret_cast<const int4*>(e_dst + b);
        if (dv.x >= lo && dv.x < hi) esrc[atomicAdd(&cursor[dv.x], 1)] = sv.x;
        if (dv.y >= lo && dv.y < hi) esrc[atomicAdd(&cursor[dv.y], 1)] = sv.y;
        if (dv.z >= lo && dv.z < hi) esrc[atomicAdd(&cursor[dv.z], 1)] = sv.z;
        if (dv.w >= lo && dv.w < hi) esrc[atomicAdd(&cursor[dv.w], 1)] = sv.w;
    } else {
        for (int k = b; k < E; ++k) {
            int d = e_dst[k];
            if (d >= lo && d < hi) esrc[atomicAdd(&cursor[d], 1)] = e_src[k];
        }
    }
}

// ---------------- Kernel 2: gather + softmax + ELU ----------------
// One wave per dst node; lane = head*8 + sub. Per 8-edge batch, lane computes
// the softmax weight for (edge k+sub, head) ONCE (64 lanes = 8 edges x 8
// heads exactly), then redistributes via shfl (ds_bpermute, LDS pipe).
__global__ __launch_bounds__(256) void gat_gather(
    const int* __restrict__ off, const int* __restrict__ esrc,
    const float* __restrict__ h, const float* __restrict__ a_src,
    const float* __restrict__ a_dst, const float* __restrict__ bias,
    float* __restrict__ out, int N)
{
    const int node = blockIdx.x * 4 + (threadIdx.x >> 6);
    if (node >= N) return;
    const int lane = threadIdx.x & 63;
    const int head = lane >> 3;
    const int sub  = lane & 7;
    const int gbase = lane & 56;      // first lane of my head group

    const float ad = a_dst[node * 8 + head];
    // self-loop
    float e0 = a_src[node * 8 + head] + ad;
    e0 = e0 > 0.f ? e0 : 0.2f * e0;
    float w0 = __expf(e0);
    float acc = w0 * h[(uint32_t)node * 64u + (uint32_t)lane];
    float s = w0;

    const int beg = off[node], end = off[node + 1];
    for (int k = beg; k < end; k += 8) {
        // my (edge, head) weight
        const int ke = k + sub;
        const int kc = ke < end ? ke : end - 1;
        const int sm = esrc[kc];
        float a = a_src[(uint32_t)sm * 8u + (uint32_t)head] + ad;
        a = a > 0.f ? a : 0.2f * a;
        const float wm = (ke < end) ? __expf(a) : 0.f;

        // h-row offsets for all 8 edges (broadcast loads, 32-bit offsets)
        uint32_t hoff[8];
        #pragma unroll
        for (int u = 0; u < 8; ++u) {
            const int kk = k + u;
            const int sb = esrc[kk < end ? kk : end - 1];
            hoff[u] = (uint32_t)sb * 64u + (uint32_t)lane;
        }
        float hb[8];
        #pragma unroll
        for (int u = 0; u < 8; ++u) hb[u] = h[hoff[u]];

        #pragma unroll
        for (int u = 0; u < 8; ++u) {
            const float w = __shfl(wm, gbase | u, 64);
            acc += w * hb[u];
            s += w;
        }
    }

    float v = acc / (s + 1e-16f) + bias[lane];
    out[(uint32_t)node * 64u + (uint32_t)lane] = v > 0.f ? v : expm1f(v);
}

extern "C" void kernel_launch(void* const* d_in, const int* in_sizes, int n_in,
                              void* d_out, int out_size, void* d_ws, size_t ws_size,
                              hipStream_t stream)
{
    const float* x       = (const float*)d_in[0];
    const float* W       = (const float*)d_in[1];
    const float* att_src = (const float*)d_in[2];
    const float* att_dst = (const float*)d_in[3];
    const float* bias    = (const float*)d_in[4];
    const int*   ei      = (const int*)d_in[5];   // int32 (JAX x64 disabled)

    const int N = in_sizes[0] / 128;
    const int E = in_sizes[5] / 2;
    const int nChunks = (N + 1023) / 1024;

    float* out = (float*)d_out;

    // workspace layout (all 4-byte elems)
    float* h        = (float*)d_ws;                    // N*64
    float* a_src    = h + (size_t)N * 64;              // N*8
    float* a_dst    = a_src + (size_t)N * 8;           // N*8
    int*   deg      = (int*)(a_dst + (size_t)N * 8);   // N
    int*   off      = deg + N;                         // N+1
    int*   cursor   = off + N + 1;                     // N
    int*   chunkSum = cursor + N;                      // nChunks
    int*   chunkBase= chunkSum + nChunks;              // nChunks
    int*   esrc     = chunkBase + nChunks;             // E

    const int* e_src = ei;
    const int* e_dst = ei + E;

    hipMemsetAsync(deg, 0, (size_t)N * sizeof(int), stream);

    gat_linear<<<(N + 15) / 16, 256, 0, stream>>>(x, W, att_src, att_dst, h, a_src, a_dst, N);

    int eb4 = (E / 4 + 256) / 256;
    gat_hist<<<eb4, 256, 0, stream>>>(e_dst, deg, E);
    gat_scan_chunks<<<nChunks, 256, 0, stream>>>(deg, off, chunkSum, N);
    gat_scan_tops<<<1, 128, 0, stream>>>(chunkSum, chunkBase, off, nChunks, N);
    gat_add_base<<<(N + 255) / 256, 256, 0, stream>>>(off, cursor, chunkBase, N);

    int nChunksE = (E + 1023) / 1024;
    gat_fill<<<nChunksE * 8, 256, 0, stream>>>(e_src, e_dst, cursor, esrc, E, N);

    gat_gather<<<(N + 3) / 4, 256, 0, stream>>>(off, esrc, h, a_src, a_dst, bias, out, N);
}

// Round 8
// 334.996 us; speedup vs baseline: 1.0098x; 1.0098x over previous
//
#include <hip/hip_runtime.h>
#include <cstdint>
#include <cstddef>

// GAT forward on MI355X — CSR-gather formulation (no f32 atomics).
// Round 8: linear -> persistent grid-stride blocks (W staged into LDS ONCE
// per block, no per-tile re-stage/barrier) + batched unroll-4 k-loop
// (16 broadcast float4 loads in flight before the FMA block) to cover
// ~300cy L2/L3 latency with ILP x TLP. Gather/CSR/fill unchanged (A/B).

// ---------------- Kernel 1: linear + logits ----------------
// Block = 256 thr (4 waves). Wave wi computes rows tile*16+wi*4..+3, lane=col.
// x rows are wave-uniform -> broadcast float4 loads (1 fetch/instr).
__global__ __launch_bounds__(256, 4) void gat_linear(
    const float* __restrict__ x, const float* __restrict__ W,
    const float* __restrict__ att_src, const float* __restrict__ att_dst,
    float* __restrict__ h, float* __restrict__ a_src, float* __restrict__ a_dst,
    int N)
{
    __shared__ float Wl[128 * 64];   // 32 KB
    const int tid  = threadIdx.x;
    const int lane = tid & 63;
    const int wi   = tid >> 6;

    for (int i = tid; i < 2048; i += 256)
        reinterpret_cast<float4*>(Wl)[i] = reinterpret_cast<const float4*>(W)[i];
    const float atts = att_src[lane];
    const float attd = att_dst[lane];
    __syncthreads();

    const int nTiles = (N + 15) / 16;
    for (int tile = blockIdx.x; tile < nTiles; tile += gridDim.x) {
        const int r0 = tile * 16 + wi * 4;
        if (r0 >= N) continue;
        const float* x0 = x + (size_t)r0 * 128;

        float acc0 = 0.f, acc1 = 0.f, acc2 = 0.f, acc3 = 0.f;
        if (r0 + 3 < N) {
            for (int kb16 = 0; kb16 < 128; kb16 += 16) {
                // batch 16 broadcast float4 loads (4 rows x 4 k4-subgroups)
                float4 xv[4][4];
                #pragma unroll
                for (int j = 0; j < 4; ++j)
                    #pragma unroll
                    for (int u = 0; u < 4; ++u)
                        xv[j][u] = *reinterpret_cast<const float4*>(
                            x0 + j * 128 + kb16 + u * 4);
                // consume: 64 FMAs, W from LDS (2-way alias = free)
                #pragma unroll
                for (int u = 0; u < 4; ++u) {
                    const int kb = kb16 + u * 4;
                    const float wa = Wl[(kb + 0) * 64 + lane];
                    const float wb = Wl[(kb + 1) * 64 + lane];
                    const float wc = Wl[(kb + 2) * 64 + lane];
                    const float wd = Wl[(kb + 3) * 64 + lane];
                    acc0 += xv[0][u].x * wa + xv[0][u].y * wb + xv[0][u].z * wc + xv[0][u].w * wd;
                    acc1 += xv[1][u].x * wa + xv[1][u].y * wb + xv[1][u].z * wc + xv[1][u].w * wd;
                    acc2 += xv[2][u].x * wa + xv[2][u].y * wb + xv[2][u].z * wc + xv[2][u].w * wd;
                    acc3 += xv[3][u].x * wa + xv[3][u].y * wb + xv[3][u].z * wc + xv[3][u].w * wd;
                }
            }
        } else {
            // tail tile (not hit at N=100000; generic safety)
            for (int k = 0; k < 128; ++k) {
                const float wv = Wl[k * 64 + lane];
                if (r0 + 0 < N) acc0 += x0[0 * 128 + k] * wv;
                if (r0 + 1 < N) acc1 += x0[1 * 128 + k] * wv;
                if (r0 + 2 < N) acc2 += x0[2 * 128 + k] * wv;
                if (r0 + 3 < N) acc3 += x0[3 * 128 + k] * wv;
            }
        }

        float accs[4] = {acc0, acc1, acc2, acc3};
        #pragma unroll
        for (int j = 0; j < 4; ++j) {
            const int node = r0 + j;
            if (node < N) {
                h[(size_t)node * 64 + lane] = accs[j];
                float vs = accs[j] * atts;
                float vd = accs[j] * attd;
                vs += __shfl_xor(vs, 1, 64); vd += __shfl_xor(vd, 1, 64);
                vs += __shfl_xor(vs, 2, 64); vd += __shfl_xor(vd, 2, 64);
                vs += __shfl_xor(vs, 4, 64); vd += __shfl_xor(vd, 4, 64);
                if ((lane & 7) == 0) {
                    a_src[node * 8 + (lane >> 3)] = vs;
                    a_dst[node * 8 + (lane >> 3)] = vd;
                }
            }
        }
    }
}

// ---------------- CSR build ----------------
__global__ __launch_bounds__(256) void gat_hist(
    const int* __restrict__ e_dst, int* __restrict__ deg, int E)
{
    int i = blockIdx.x * 256 + threadIdx.x;
    int b = i * 4;
    if (b + 3 < E) {
        int4 d = *reinterpret_cast<const int4*>(e_dst + b);
        atomicAdd(&deg[d.x], 1);
        atomicAdd(&deg[d.y], 1);
        atomicAdd(&deg[d.z], 1);
        atomicAdd(&deg[d.w], 1);
    } else {
        for (int k = b; k < E; ++k) atomicAdd(&deg[e_dst[k]], 1);
    }
}

// Per-chunk (1024 elems) exclusive scan; chunkSum[b] = chunk total.
__global__ __launch_bounds__(256) void gat_scan_chunks(
    const int* __restrict__ deg, int* __restrict__ off,
    int* __restrict__ chunkSum, int N)
{
    __shared__ int lds[256];
    const int t = threadIdx.x;
    const int base = blockIdx.x * 1024 + t * 4;
    int v0 = 0, v1 = 0, v2 = 0, v3 = 0;
    if (base + 0 < N) v0 = deg[base + 0];
    if (base + 1 < N) v1 = deg[base + 1];
    if (base + 2 < N) v2 = deg[base + 2];
    if (base + 3 < N) v3 = deg[base + 3];
    int s = v0 + v1 + v2 + v3;
    lds[t] = s;
    __syncthreads();
    #pragma unroll
    for (int d = 1; d < 256; d <<= 1) {
        int add = (t >= d) ? lds[t - d] : 0;
        __syncthreads();
        lds[t] += add;
        __syncthreads();
    }
    if (t == 255) chunkSum[blockIdx.x] = lds[255];
    int p = lds[t] - s;  // exclusive within chunk
    if (base + 0 < N) off[base + 0] = p; p += v0;
    if (base + 1 < N) off[base + 1] = p; p += v1;
    if (base + 2 < N) off[base + 2] = p; p += v2;
    if (base + 3 < N) off[base + 3] = p;
}

// Exclusive scan of chunk sums (nChunks <= 128) in one 128-thread block.
__global__ __launch_bounds__(128) void gat_scan_tops(
    const int* __restrict__ chunkSum, int* __restrict__ chunkBase,
    int* __restrict__ off, int nChunks, int N)
{
    __shared__ int lds[128];
    const int t = threadIdx.x;
    if (nChunks > 128) {               // safety fallback (not hit at N=100k)
        if (t == 0) {
            int run = 0;
            for (int i = 0; i < nChunks; ++i) { chunkBase[i] = run; run += chunkSum[i]; }
            off[N] = run;
        }
        return;
    }
    int v = (t < nChunks) ? chunkSum[t] : 0;
    lds[t] = v;
    __syncthreads();
    #pragma unroll
    for (int d = 1; d < 128; d <<= 1) {
        int add = (t >= d) ? lds[t - d] : 0;
        __syncthreads();
        lds[t] += add;
        __syncthreads();
    }
    if (t < nChunks) chunkBase[t] = lds[t] - v;
    if (t == nChunks - 1) off[N] = lds[t];
}

__global__ __launch_bounds__(256) void gat_add_base(
    int* __restrict__ off, int* __restrict__ cursor,
    const int* __restrict__ chunkBase, int N)
{
    int i = blockIdx.x * 256 + threadIdx.x;
    if (i < N) {
        int v = off[i] + chunkBase[i >> 10];
        off[i] = v;
        cursor[i] = v;
    }
}

// dst-range-partitioned fill (see round 5 notes).
__global__ __launch_bounds__(256) void gat_fill(
    const int* __restrict__ e_src, const int* __restrict__ e_dst,
    int* __restrict__ cursor, int* __restrict__ esrc, int E, int N)
{
    const int range = blockIdx.x & 7;
    const int chunk = blockIdx.x >> 3;
    const int lo = (int)(((long long)N * range) >> 3);
    const int hi = (int)(((long long)N * (range + 1)) >> 3);

    const int b = chunk * 1024 + threadIdx.x * 4;
    if (b + 3 < E) {
        int4 sv = *reinterpret_cast<const int4*>(e_src + b);
        int4 dv = *reinterpret_cast<const int4*>(e_dst + b);
        if (dv.x >= lo && dv.x < hi) esrc[atomicAdd(&cursor[dv.x], 1)] = sv.x;
        if (dv.y >= lo && dv.y < hi) esrc[atomicAdd(&cursor[dv.y], 1)] = sv.y;
        if (dv.z >= lo && dv.z < hi) esrc[atomicAdd(&cursor[dv.z], 1)] = sv.z;
        if (dv.w >= lo && dv.w < hi) esrc[atomicAdd(&cursor[dv.w], 1)] = sv.w;
    } else {
        for (int k = b; k < E; ++k) {
            int d = e_dst[k];
            if (d >= lo && d < hi) esrc[atomicAdd(&cursor[d], 1)] = e_src[k];
        }
    }
}

// ---------------- Kernel 2: gather + softmax + ELU ----------------
// One wave per dst node; lane = head*8 + sub. Per 8-edge batch, lane computes
// the softmax weight for (edge k+sub, head) ONCE (64 lanes = 8 edges x 8
// heads exactly), then redistributes via shfl (ds_bpermute, LDS pipe).
__global__ __launch_bounds__(256) void gat_gather(
    const int* __restrict__ off, const int* __restrict__ esrc,
    const float* __restrict__ h, const float* __restrict__ a_src,
    const float* __restrict__ a_dst, const float* __restrict__ bias,
    float* __restrict__ out, int N)
{
    const int node = blockIdx.x * 4 + (threadIdx.x >> 6);
    if (node >= N) return;
    const int lane = threadIdx.x & 63;
    const int head = lane >> 3;
    const int sub  = lane & 7;
    const int gbase = lane & 56;      // first lane of my head group

    const float ad = a_dst[node * 8 + head];
    // self-loop
    float e0 = a_src[node * 8 + head] + ad;
    e0 = e0 > 0.f ? e0 : 0.2f * e0;
    float w0 = __expf(e0);
    float acc = w0 * h[(uint32_t)node * 64u + (uint32_t)lane];
    float s = w0;

    const int beg = off[node], end = off[node + 1];
    for (int k = beg; k < end; k += 8) {
        // my (edge, head) weight
        const int ke = k + sub;
        const int kc = ke < end ? ke : end - 1;
        const int sm = esrc[kc];
        float a = a_src[(uint32_t)sm * 8u + (uint32_t)head] + ad;
        a = a > 0.f ? a : 0.2f * a;
        const float wm = (ke < end) ? __expf(a) : 0.f;

        // h-row offsets for all 8 edges (broadcast loads, 32-bit offsets)
        uint32_t hoff[8];
        #pragma unroll
        for (int u = 0; u < 8; ++u) {
            const int kk = k + u;
            const int sb = esrc[kk < end ? kk : end - 1];
            hoff[u] = (uint32_t)sb * 64u + (uint32_t)lane;
        }
        float hb[8];
        #pragma unroll
        for (int u = 0; u < 8; ++u) hb[u] = h[hoff[u]];

        #pragma unroll
        for (int u = 0; u < 8; ++u) {
            const float w = __shfl(wm, gbase | u, 64);
            acc += w * hb[u];
            s += w;
        }
    }

    float v = acc / (s + 1e-16f) + bias[lane];
    out[(uint32_t)node * 64u + (uint32_t)lane] = v > 0.f ? v : expm1f(v);
}

extern "C" void kernel_launch(void* const* d_in, const int* in_sizes, int n_in,
                              void* d_out, int out_size, void* d_ws, size_t ws_size,
                              hipStream_t stream)
{
    const float* x       = (const float*)d_in[0];
    const float* W       = (const float*)d_in[1];
    const float* att_src = (const float*)d_in[2];
    const float* att_dst = (const float*)d_in[3];
    const float* bias    = (const float*)d_in[4];
    const int*   ei      = (const int*)d_in[5];   // int32 (JAX x64 disabled)

    const int N = in_sizes[0] / 128;
    const int E = in_sizes[5] / 2;
    const int nChunks = (N + 1023) / 1024;

    float* out = (float*)d_out;

    // workspace layout (all 4-byte elems)
    float* h        = (float*)d_ws;                    // N*64
    float* a_src    = h + (size_t)N * 64;              // N*8
    float* a_dst    = a_src + (size_t)N * 8;           // N*8
    int*   deg      = (int*)(a_dst + (size_t)N * 8);   // N
    int*   off      = deg + N;                         // N+1
    int*   cursor   = off + N + 1;                     // N
    int*   chunkSum = cursor + N;                      // nChunks
    int*   chunkBase= chunkSum + nChunks;              // nChunks
    int*   esrc     = chunkBase + nChunks;             // E

    const int* e_src = ei;
    const int* e_dst = ei + E;

    hipMemsetAsync(deg, 0, (size_t)N * sizeof(int), stream);

    gat_linear<<<1280, 256, 0, stream>>>(x, W, att_src, att_dst, h, a_src, a_dst, N);

    int eb4 = (E / 4 + 256) / 256;
    gat_hist<<<eb4, 256, 0, stream>>>(e_dst, deg, E);
    gat_scan_chunks<<<nChunks, 256, 0, stream>>>(deg, off, chunkSum, N);
    gat_scan_tops<<<1, 128, 0, stream>>>(chunkSum, chunkBase, off, nChunks, N);
    gat_add_base<<<(N + 255) / 256, 256, 0, stream>>>(off, cursor, chunkBase, N);

    int nChunksE = (E + 1023) / 1024;
    gat_fill<<<nChunksE * 8, 256, 0, stream>>>(e_src, e_dst, cursor, esrc, E, N);

    gat_gather<<<(N + 3) / 4, 256, 0, stream>>>(off, esrc, h, a_src, a_dst, bias, out, N);
}

// Round 9
// 258.589 us; speedup vs baseline: 1.3082x; 1.2955x over previous
//
#include <hip/hip_runtime.h>
#include <cstdint>
#include <cstddef>

// GAT forward on MI355X — CSR-gather formulation (no f32 atomics).
// Round 9: linear -> MFMA bf16 (mfma_f32_16x16x32_bf16). x,W rounded to bf16
// in-register / in-LDS, f32 accumulate; h + fused logits epilogue from the
// verified C/D layout (col=lane&15, row=(lane>>4)*4+reg). Gather/CSR/fill
// unchanged from round 8 (clean A/B on the linear).

typedef __attribute__((ext_vector_type(8))) short short8v;  // 8 bf16 (4 VGPR)
typedef __attribute__((ext_vector_type(4))) float f32x4;    // acc (4 VGPR)

__device__ __forceinline__ unsigned short f2bf(float f) {
    unsigned u = __float_as_uint(f);
    unsigned r = u + 0x7FFFu + ((u >> 16) & 1u);   // round-to-nearest-even
    return (unsigned short)(r >> 16);
}

// ---------------- Kernel 1: linear + logits (MFMA) ----------------
// Block = 256 thr (4 waves). One 64-row x 64-col tile per block; wave wi owns
// rows r0+wi*16..+15. B (=W) frags preloaded from transposed bf16 LDS copy.
__global__ __launch_bounds__(256) void gat_linear_mfma(
    const float* __restrict__ x, const float* __restrict__ W,
    const float* __restrict__ att_src, const float* __restrict__ att_dst,
    float* __restrict__ h, float* __restrict__ a_src, float* __restrict__ a_dst,
    int N)
{
    __shared__ unsigned short Wt[64][136];   // transposed, padded (16B rows)
    const int tid  = threadIdx.x;
    const int lane = tid & 63;
    const int wi   = tid >> 6;

    // stage W (128x64 f32, row-major) -> Wt[col][k] bf16
    for (int i = tid; i < 8192; i += 256) {
        const int k = i >> 6, col = i & 63;
        Wt[col][k] = f2bf(W[i]);
    }
    __syncthreads();

    const int r0   = blockIdx.x * 64 + wi * 16;
    const int lrow = lane & 15;
    const int kgrp = (lane >> 4) * 8;        // my 8-element k-offset
    const int row  = r0 + lrow;
    const int rowc = row < N ? row : N - 1;  // clamp for loads; stores guarded

    // B frags: col = lrow + 16c, k = t*32 + kgrp + j
    short8v bf[4][4];
    #pragma unroll
    for (int t = 0; t < 4; ++t)
        #pragma unroll
        for (int c = 0; c < 4; ++c)
            bf[t][c] = *reinterpret_cast<const short8v*>(&Wt[lrow + 16 * c][t * 32 + kgrp]);

    // A loads: my row, 8 floats per K-step (2 float4s)
    const float* xr = x + (size_t)rowc * 128 + kgrp;
    float4 xa[4][2];
    #pragma unroll
    for (int t = 0; t < 4; ++t) {
        xa[t][0] = *reinterpret_cast<const float4*>(xr + t * 32);
        xa[t][1] = *reinterpret_cast<const float4*>(xr + t * 32 + 4);
    }

    f32x4 acc[4] = {f32x4{0,0,0,0}, f32x4{0,0,0,0}, f32x4{0,0,0,0}, f32x4{0,0,0,0}};
    #pragma unroll
    for (int t = 0; t < 4; ++t) {
        short8v af;
        af[0] = (short)f2bf(xa[t][0].x); af[1] = (short)f2bf(xa[t][0].y);
        af[2] = (short)f2bf(xa[t][0].z); af[3] = (short)f2bf(xa[t][0].w);
        af[4] = (short)f2bf(xa[t][1].x); af[5] = (short)f2bf(xa[t][1].y);
        af[6] = (short)f2bf(xa[t][1].z); af[7] = (short)f2bf(xa[t][1].w);
        #pragma unroll
        for (int c = 0; c < 4; ++c)
            acc[c] = __builtin_amdgcn_mfma_f32_16x16x32_bf16(af, bf[t][c], acc[c], 0, 0, 0);
    }

    // epilogue: C/D layout col = lrow + 16c, row = r0 + (lane>>4)*4 + reg
    const int g = lane >> 4;
    float attS[4], attD[4];
    #pragma unroll
    for (int c = 0; c < 4; ++c) {
        attS[c] = att_src[lrow + 16 * c];
        attD[c] = att_dst[lrow + 16 * c];
    }

    #pragma unroll
    for (int reg = 0; reg < 4; ++reg) {
        const int r = r0 + g * 4 + reg;
        if (r < N) {   // uniform within each 16-lane group -> shfl-safe
            #pragma unroll
            for (int c = 0; c < 4; ++c) {
                const float v = acc[c][reg];
                h[(size_t)r * 64 + lrow + 16 * c] = v;
                float vs = v * attS[c];
                float vd = v * attD[c];
                vs += __shfl_xor(vs, 1, 64); vd += __shfl_xor(vd, 1, 64);
                vs += __shfl_xor(vs, 2, 64); vd += __shfl_xor(vd, 2, 64);
                vs += __shfl_xor(vs, 4, 64); vd += __shfl_xor(vd, 4, 64);
                if ((lane & 7) == 0) {
                    const int head = ((lane & 8) >> 3) + 2 * c;
                    a_src[r * 8 + head] = vs;
                    a_dst[r * 8 + head] = vd;
                }
            }
        }
    }
}

// ---------------- CSR build ----------------
__global__ __launch_bounds__(256) void gat_hist(
    const int* __restrict__ e_dst, int* __restrict__ deg, int E)
{
    int i = blockIdx.x * 256 + threadIdx.x;
    int b = i * 4;
    if (b + 3 < E) {
        int4 d = *reinterpret_cast<const int4*>(e_dst + b);
        atomicAdd(&deg[d.x], 1);
        atomicAdd(&deg[d.y], 1);
        atomicAdd(&deg[d.z], 1);
        atomicAdd(&deg[d.w], 1);
    } else {
        for (int k = b; k < E; ++k) atomicAdd(&deg[e_dst[k]], 1);
    }
}

// Per-chunk (1024 elems) exclusive scan; chunkSum[b] = chunk total.
__global__ __launch_bounds__(256) void gat_scan_chunks(
    const int* __restrict__ deg, int* __restrict__ off,
    int* __restrict__ chunkSum, int N)
{
    __shared__ int lds[256];
    const int t = threadIdx.x;
    const int base = blockIdx.x * 1024 + t * 4;
    int v0 = 0, v1 = 0, v2 = 0, v3 = 0;
    if (base + 0 < N) v0 = deg[base + 0];
    if (base + 1 < N) v1 = deg[base + 1];
    if (base + 2 < N) v2 = deg[base + 2];
    if (base + 3 < N) v3 = deg[base + 3];
    int s = v0 + v1 + v2 + v3;
    lds[t] = s;
    __syncthreads();
    #pragma unroll
    for (int d = 1; d < 256; d <<= 1) {
        int add = (t >= d) ? lds[t - d] : 0;
        __syncthreads();
        lds[t] += add;
        __syncthreads();
    }
    if (t == 255) chunkSum[blockIdx.x] = lds[255];
    int p = lds[t] - s;  // exclusive within chunk
    if (base + 0 < N) off[base + 0] = p; p += v0;
    if (base + 1 < N) off[base + 1] = p; p += v1;
    if (base + 2 < N) off[base + 2] = p; p += v2;
    if (base + 3 < N) off[base + 3] = p;
}

// Exclusive scan of chunk sums (nChunks <= 128) in one 128-thread block.
__global__ __launch_bounds__(128) void gat_scan_tops(
    const int* __restrict__ chunkSum, int* __restrict__ chunkBase,
    int* __restrict__ off, int nChunks, int N)
{
    __shared__ int lds[128];
    const int t = threadIdx.x;
    if (nChunks > 128) {               // safety fallback (not hit at N=100k)
        if (t == 0) {
            int run = 0;
            for (int i = 0; i < nChunks; ++i) { chunkBase[i] = run; run += chunkSum[i]; }
            off[N] = run;
        }
        return;
    }
    int v = (t < nChunks) ? chunkSum[t] : 0;
    lds[t] = v;
    __syncthreads();
    #pragma unroll
    for (int d = 1; d < 128; d <<= 1) {
        int add = (t >= d) ? lds[t - d] : 0;
        __syncthreads();
        lds[t] += add;
        __syncthreads();
    }
    if (t < nChunks) chunkBase[t] = lds[t] - v;
    if (t == nChunks - 1) off[N] = lds[t];
}

__global__ __launch_bounds__(256) void gat_add_base(
    int* __restrict__ off, int* __restrict__ cursor,
    const int* __restrict__ chunkBase, int N)
{
    int i = blockIdx.x * 256 + threadIdx.x;
    if (i < N) {
        int v = off[i] + chunkBase[i >> 10];
        off[i] = v;
        cursor[i] = v;
    }
}

// dst-range-partitioned fill (see round 5 notes).
__global__ __launch_bounds__(256) void gat_fill(
    const int* __restrict__ e_src, const int* __restrict__ e_dst,
    int* __restrict__ cursor, int* __restrict__ esrc, int E, int N)
{
    const int range = blockIdx.x & 7;
    const int chunk = blockIdx.x >> 3;
    const int lo = (int)(((long long)N * range) >> 3);
    const int hi = (int)(((long long)N * (range + 1)) >> 3);

    const int b = chunk * 1024 + threadIdx.x * 4;
    if (b + 3 < E) {
        int4 sv = *reinterpret_cast<const int4*>(e_src + b);
        int4 dv = *reinterpret_cast<const int4*>(e_dst + b);
        if (dv.x >= lo && dv.x < hi) esrc[atomicAdd(&cursor[dv.x], 1)] = sv.x;
        if (dv.y >= lo && dv.y < hi) esrc[atomicAdd(&cursor[dv.y], 1)] = sv.y;
        if (dv.z >= lo && dv.z < hi) esrc[atomicAdd(&cursor[dv.z], 1)] = sv.z;
        if (dv.w >= lo && dv.w < hi) esrc[atomicAdd(&cursor[dv.w], 1)] = sv.w;
    } else {
        for (int k = b; k < E; ++k) {
            int d = e_dst[k];
            if (d >= lo && d < hi) esrc[atomicAdd(&cursor[d], 1)] = e_src[k];
        }
    }
}

// ---------------- Kernel 2: gather + softmax + ELU ----------------
// One wave per dst node; lane = head*8 + sub. Per 8-edge batch, lane computes
// the softmax weight for (edge k+sub, head) ONCE, then redistributes via shfl.
__global__ __launch_bounds__(256) void gat_gather(
    const int* __restrict__ off, const int* __restrict__ esrc,
    const float* __restrict__ h, const float* __restrict__ a_src,
    const float* __restrict__ a_dst, const float* __restrict__ bias,
    float* __restrict__ out, int N)
{
    const int node = blockIdx.x * 4 + (threadIdx.x >> 6);
    if (node >= N) return;
    const int lane = threadIdx.x & 63;
    const int head = lane >> 3;
    const int sub  = lane & 7;
    const int gbase = lane & 56;      // first lane of my head group

    const float ad = a_dst[node * 8 + head];
    // self-loop
    float e0 = a_src[node * 8 + head] + ad;
    e0 = e0 > 0.f ? e0 : 0.2f * e0;
    float w0 = __expf(e0);
    float acc = w0 * h[(uint32_t)node * 64u + (uint32_t)lane];
    float s = w0;

    const int beg = off[node], end = off[node + 1];
    for (int k = beg; k < end; k += 8) {
        const int ke = k + sub;
        const int kc = ke < end ? ke : end - 1;
        const int sm = esrc[kc];
        float a = a_src[(uint32_t)sm * 8u + (uint32_t)head] + ad;
        a = a > 0.f ? a : 0.2f * a;
        const float wm = (ke < end) ? __expf(a) : 0.f;

        uint32_t hoff[8];
        #pragma unroll
        for (int u = 0; u < 8; ++u) {
            const int kk = k + u;
            const int sb = esrc[kk < end ? kk : end - 1];
            hoff[u] = (uint32_t)sb * 64u + (uint32_t)lane;
        }
        float hb[8];
        #pragma unroll
        for (int u = 0; u < 8; ++u) hb[u] = h[hoff[u]];

        #pragma unroll
        for (int u = 0; u < 8; ++u) {
            const float w = __shfl(wm, gbase | u, 64);
            acc += w * hb[u];
            s += w;
        }
    }

    float v = acc / (s + 1e-16f) + bias[lane];
    out[(uint32_t)node * 64u + (uint32_t)lane] = v > 0.f ? v : expm1f(v);
}

extern "C" void kernel_launch(void* const* d_in, const int* in_sizes, int n_in,
                              void* d_out, int out_size, void* d_ws, size_t ws_size,
                              hipStream_t stream)
{
    const float* x       = (const float*)d_in[0];
    const float* W       = (const float*)d_in[1];
    const float* att_src = (const float*)d_in[2];
    const float* att_dst = (const float*)d_in[3];
    const float* bias    = (const float*)d_in[4];
    const int*   ei      = (const int*)d_in[5];   // int32 (JAX x64 disabled)

    const int N = in_sizes[0] / 128;
    const int E = in_sizes[5] / 2;
    const int nChunks = (N + 1023) / 1024;

    float* out = (float*)d_out;

    // workspace layout (all 4-byte elems)
    float* h        = (float*)d_ws;                    // N*64
    float* a_src    = h + (size_t)N * 64;              // N*8
    float* a_dst    = a_src + (size_t)N * 8;           // N*8
    int*   deg      = (int*)(a_dst + (size_t)N * 8);   // N
    int*   off      = deg + N;                         // N+1
    int*   cursor   = off + N + 1;                     // N
    int*   chunkSum = cursor + N;                      // nChunks
    int*   chunkBase= chunkSum + nChunks;              // nChunks
    int*   esrc     = chunkBase + nChunks;             // E

    const int* e_src = ei;
    const int* e_dst = ei + E;

    hipMemsetAsync(deg, 0, (size_t)N * sizeof(int), stream);

    gat_linear_mfma<<<(N + 63) / 64, 256, 0, stream>>>(
        x, W, att_src, att_dst, h, a_src, a_dst, N);

    int eb4 = (E / 4 + 256) / 256;
    gat_hist<<<eb4, 256, 0, stream>>>(e_dst, deg, E);
    gat_scan_chunks<<<nChunks, 256, 0, stream>>>(deg, off, chunkSum, N);
    gat_scan_tops<<<1, 128, 0, stream>>>(chunkSum, chunkBase, off, nChunks, N);
    gat_add_base<<<(N + 255) / 256, 256, 0, stream>>>(off, cursor, chunkBase, N);

    int nChunksE = (E + 1023) / 1024;
    gat_fill<<<nChunksE * 8, 256, 0, stream>>>(e_src, e_dst, cursor, esrc, E, N);

    gat_gather<<<(N + 3) / 4, 256, 0, stream>>>(off, esrc, h, a_src, a_dst, bias, out, N);
}

// Round 10
// 198.428 us; speedup vs baseline: 1.7048x; 1.3032x over previous
//
#include <hip/hip_runtime.h>
#include <cstdint>
#include <cstddef>

// GAT forward on MI355X — CSR-gather formulation (no f32 atomics).
// Round 10: (1) h stored bf16 -> gather random-read bytes halved;
// (2) gather reads esrc once/lane, redistributes src via shfl;
// (3) fill atomic-free: rank captured during hist (atomicAdd return),
//     fill = partitioned pure scatter at off[dst]+rank.

typedef __attribute__((ext_vector_type(8))) short short8v;  // 8 bf16 (4 VGPR)
typedef __attribute__((ext_vector_type(4))) float f32x4;    // acc (4 VGPR)

__device__ __forceinline__ unsigned short f2bf(float f) {
    unsigned u = __float_as_uint(f);
    unsigned r = u + 0x7FFFu + ((u >> 16) & 1u);   // round-to-nearest-even
    return (unsigned short)(r >> 16);
}
__device__ __forceinline__ float bf2f(unsigned short u) {
    return __uint_as_float(((unsigned)u) << 16);
}

// ---------------- Kernel 1: linear + logits (MFMA) ----------------
// Block = 256 thr (4 waves). One 64x64 tile per block; wave wi owns rows
// r0+wi*16..+15. mfma_f32_16x16x32_bf16; C/D: col=lane&15, row=(lane>>4)*4+reg.
__global__ __launch_bounds__(256) void gat_linear_mfma(
    const float* __restrict__ x, const float* __restrict__ W,
    const float* __restrict__ att_src, const float* __restrict__ att_dst,
    unsigned short* __restrict__ h_bf, float* __restrict__ a_src,
    float* __restrict__ a_dst, int N)
{
    __shared__ unsigned short Wt[64][136];   // transposed, padded (16B rows)
    const int tid  = threadIdx.x;
    const int lane = tid & 63;
    const int wi   = tid >> 6;

    for (int i = tid; i < 8192; i += 256) {
        const int k = i >> 6, col = i & 63;
        Wt[col][k] = f2bf(W[i]);
    }
    __syncthreads();

    const int r0   = blockIdx.x * 64 + wi * 16;
    const int lrow = lane & 15;
    const int kgrp = (lane >> 4) * 8;
    const int row  = r0 + lrow;
    const int rowc = row < N ? row : N - 1;

    short8v bf[4][4];
    #pragma unroll
    for (int t = 0; t < 4; ++t)
        #pragma unroll
        for (int c = 0; c < 4; ++c)
            bf[t][c] = *reinterpret_cast<const short8v*>(&Wt[lrow + 16 * c][t * 32 + kgrp]);

    const float* xr = x + (size_t)rowc * 128 + kgrp;
    float4 xa[4][2];
    #pragma unroll
    for (int t = 0; t < 4; ++t) {
        xa[t][0] = *reinterpret_cast<const float4*>(xr + t * 32);
        xa[t][1] = *reinterpret_cast<const float4*>(xr + t * 32 + 4);
    }

    f32x4 acc[4] = {f32x4{0,0,0,0}, f32x4{0,0,0,0}, f32x4{0,0,0,0}, f32x4{0,0,0,0}};
    #pragma unroll
    for (int t = 0; t < 4; ++t) {
        short8v af;
        af[0] = (short)f2bf(xa[t][0].x); af[1] = (short)f2bf(xa[t][0].y);
        af[2] = (short)f2bf(xa[t][0].z); af[3] = (short)f2bf(xa[t][0].w);
        af[4] = (short)f2bf(xa[t][1].x); af[5] = (short)f2bf(xa[t][1].y);
        af[6] = (short)f2bf(xa[t][1].z); af[7] = (short)f2bf(xa[t][1].w);
        #pragma unroll
        for (int c = 0; c < 4; ++c)
            acc[c] = __builtin_amdgcn_mfma_f32_16x16x32_bf16(af, bf[t][c], acc[c], 0, 0, 0);
    }

    const int g = lane >> 4;
    float attS[4], attD[4];
    #pragma unroll
    for (int c = 0; c < 4; ++c) {
        attS[c] = att_src[lrow + 16 * c];
        attD[c] = att_dst[lrow + 16 * c];
    }

    #pragma unroll
    for (int reg = 0; reg < 4; ++reg) {
        const int r = r0 + g * 4 + reg;
        if (r < N) {   // uniform within each 16-lane group -> shfl-safe
            #pragma unroll
            for (int c = 0; c < 4; ++c) {
                const float v = acc[c][reg];
                h_bf[(size_t)r * 64 + lrow + 16 * c] = f2bf(v);
                float vs = v * attS[c];
                float vd = v * attD[c];
                vs += __shfl_xor(vs, 1, 64); vd += __shfl_xor(vd, 1, 64);
                vs += __shfl_xor(vs, 2, 64); vd += __shfl_xor(vd, 2, 64);
                vs += __shfl_xor(vs, 4, 64); vd += __shfl_xor(vd, 4, 64);
                if ((lane & 7) == 0) {
                    const int head = ((lane & 8) >> 3) + 2 * c;
                    a_src[r * 8 + head] = vs;
                    a_dst[r * 8 + head] = vd;
                }
            }
        }
    }
}

// ---------------- CSR build ----------------
// histogram + per-edge rank (atomicAdd return value)
__global__ __launch_bounds__(256) void gat_hist_rank(
    const int* __restrict__ e_dst, int* __restrict__ deg,
    int* __restrict__ rank, int E)
{
    int i = blockIdx.x * 256 + threadIdx.x;
    int b = i * 4;
    if (b + 3 < E) {
        int4 d = *reinterpret_cast<const int4*>(e_dst + b);
        int4 r;
        r.x = atomicAdd(&deg[d.x], 1);
        r.y = atomicAdd(&deg[d.y], 1);
        r.z = atomicAdd(&deg[d.z], 1);
        r.w = atomicAdd(&deg[d.w], 1);
        *reinterpret_cast<int4*>(rank + b) = r;
    } else {
        for (int k = b; k < E; ++k) rank[k] = atomicAdd(&deg[e_dst[k]], 1);
    }
}

// Per-chunk (1024 elems) exclusive scan; chunkSum[b] = chunk total.
__global__ __launch_bounds__(256) void gat_scan_chunks(
    const int* __restrict__ deg, int* __restrict__ off,
    int* __restrict__ chunkSum, int N)
{
    __shared__ int lds[256];
    const int t = threadIdx.x;
    const int base = blockIdx.x * 1024 + t * 4;
    int v0 = 0, v1 = 0, v2 = 0, v3 = 0;
    if (base + 0 < N) v0 = deg[base + 0];
    if (base + 1 < N) v1 = deg[base + 1];
    if (base + 2 < N) v2 = deg[base + 2];
    if (base + 3 < N) v3 = deg[base + 3];
    int s = v0 + v1 + v2 + v3;
    lds[t] = s;
    __syncthreads();
    #pragma unroll
    for (int d = 1; d < 256; d <<= 1) {
        int add = (t >= d) ? lds[t - d] : 0;
        __syncthreads();
        lds[t] += add;
        __syncthreads();
    }
    if (t == 255) chunkSum[blockIdx.x] = lds[255];
    int p = lds[t] - s;  // exclusive within chunk
    if (base + 0 < N) off[base + 0] = p; p += v0;
    if (base + 1 < N) off[base + 1] = p; p += v1;
    if (base + 2 < N) off[base + 2] = p; p += v2;
    if (base + 3 < N) off[base + 3] = p;
}

// Exclusive scan of chunk sums (nChunks <= 128) in one 128-thread block.
__global__ __launch_bounds__(128) void gat_scan_tops(
    const int* __restrict__ chunkSum, int* __restrict__ chunkBase,
    int* __restrict__ off, int nChunks, int N)
{
    __shared__ int lds[128];
    const int t = threadIdx.x;
    if (nChunks > 128) {               // safety fallback (not hit at N=100k)
        if (t == 0) {
            int run = 0;
            for (int i = 0; i < nChunks; ++i) { chunkBase[i] = run; run += chunkSum[i]; }
            off[N] = run;
        }
        return;
    }
    int v = (t < nChunks) ? chunkSum[t] : 0;
    lds[t] = v;
    __syncthreads();
    #pragma unroll
    for (int d = 1; d < 128; d <<= 1) {
        int add = (t >= d) ? lds[t - d] : 0;
        __syncthreads();
        lds[t] += add;
        __syncthreads();
    }
    if (t < nChunks) chunkBase[t] = lds[t] - v;
    if (t == nChunks - 1) off[N] = lds[t];
}

__global__ __launch_bounds__(256) void gat_add_base(
    int* __restrict__ off, const int* __restrict__ chunkBase, int N)
{
    int i = blockIdx.x * 256 + threadIdx.x;
    if (i < N) off[i] += chunkBase[i >> 10];
}

// dst-range-partitioned, ATOMIC-FREE fill: pos = off[dst] + rank (unique).
// Grid = nChunksE * 8; range = bid & 7 (XCD-affine); each block scans one
// 1024-edge chunk and scatters only its range's edges -> per-range esrc
// slice (~0.8 MB) stays cache-resident. Edge re-reads (8x) served by L3.
__global__ __launch_bounds__(256) void gat_fill(
    const int* __restrict__ e_src, const int* __restrict__ e_dst,
    const int* __restrict__ rank, const int* __restrict__ off,
    int* __restrict__ esrc, int E, int N)
{
    const int range = blockIdx.x & 7;
    const int chunk = blockIdx.x >> 3;
    const int lo = (int)(((long long)N * range) >> 3);
    const int hi = (int)(((long long)N * (range + 1)) >> 3);

    const int b = chunk * 1024 + threadIdx.x * 4;
    if (b + 3 < E) {
        int4 sv = *reinterpret_cast<const int4*>(e_src + b);
        int4 dv = *reinterpret_cast<const int4*>(e_dst + b);
        int4 rv = *reinterpret_cast<const int4*>(rank + b);
        if (dv.x >= lo && dv.x < hi) esrc[off[dv.x] + rv.x] = sv.x;
        if (dv.y >= lo && dv.y < hi) esrc[off[dv.y] + rv.y] = sv.y;
        if (dv.z >= lo && dv.z < hi) esrc[off[dv.z] + rv.z] = sv.z;
        if (dv.w >= lo && dv.w < hi) esrc[off[dv.w] + rv.w] = sv.w;
    } else {
        for (int k = b; k < E; ++k) {
            int d = e_dst[k];
            if (d >= lo && d < hi) esrc[off[d] + rank[k]] = e_src[k];
        }
    }
}

// ---------------- Kernel 2: gather + softmax + ELU ----------------
// One wave per dst node; lane = head*8 + sub. Per 8-edge batch: lane reads
// esrc ONCE (edge k+sub), computes that edge's weight for its head, then
// both src index and weight are redistributed via shfl. h read as bf16.
__global__ __launch_bounds__(256) void gat_gather(
    const int* __restrict__ off, const int* __restrict__ esrc,
    const unsigned short* __restrict__ h_bf, const float* __restrict__ a_src,
    const float* __restrict__ a_dst, const float* __restrict__ bias,
    float* __restrict__ out, int N)
{
    const int node = blockIdx.x * 4 + (threadIdx.x >> 6);
    if (node >= N) return;
    const int lane = threadIdx.x & 63;
    const int head = lane >> 3;
    const int sub  = lane & 7;
    const int gbase = lane & 56;      // first lane of my head group

    const float ad = a_dst[node * 8 + head];
    // self-loop
    float e0 = a_src[node * 8 + head] + ad;
    e0 = e0 > 0.f ? e0 : 0.2f * e0;
    float w0 = __expf(e0);
    float acc = w0 * bf2f(h_bf[(uint32_t)node * 64u + (uint32_t)lane]);
    float s = w0;

    const int beg = off[node], end = off[node + 1];
    for (int k = beg; k < end; k += 8) {
        // my edge: index + weight for my head
        const int ke = k + sub;
        const int kc = ke < end ? ke : end - 1;
        const int sm = esrc[kc];
        float a = a_src[(uint32_t)sm * 8u + (uint32_t)head] + ad;
        a = a > 0.f ? a : 0.2f * a;
        const float wm = (ke < end) ? __expf(a) : 0.f;

        // redistribute src indices; issue all 8 h loads (bf16, coalesced)
        uint32_t hoff[8];
        #pragma unroll
        for (int u = 0; u < 8; ++u) {
            const int sb = __shfl(sm, gbase | u, 64);
            hoff[u] = (uint32_t)sb * 64u + (uint32_t)lane;
        }
        float hb[8];
        #pragma unroll
        for (int u = 0; u < 8; ++u) hb[u] = bf2f(h_bf[hoff[u]]);

        #pragma unroll
        for (int u = 0; u < 8; ++u) {
            const float w = __shfl(wm, gbase | u, 64);
            acc += w * hb[u];
            s += w;
        }
    }

    float v = acc / (s + 1e-16f) + bias[lane];
    out[(uint32_t)node * 64u + (uint32_t)lane] = v > 0.f ? v : expm1f(v);
}

extern "C" void kernel_launch(void* const* d_in, const int* in_sizes, int n_in,
                              void* d_out, int out_size, void* d_ws, size_t ws_size,
                              hipStream_t stream)
{
    const float* x       = (const float*)d_in[0];
    const float* W       = (const float*)d_in[1];
    const float* att_src = (const float*)d_in[2];
    const float* att_dst = (const float*)d_in[3];
    const float* bias    = (const float*)d_in[4];
    const int*   ei      = (const int*)d_in[5];   // int32 (JAX x64 disabled)

    const int N = in_sizes[0] / 128;
    const int E = in_sizes[5] / 2;
    const int nChunks = (N + 1023) / 1024;

    float* out = (float*)d_out;

    // workspace layout
    unsigned short* h_bf = (unsigned short*)d_ws;          // N*64 bf16
    float* a_src    = (float*)(h_bf + (size_t)N * 64);     // N*8 f32
    float* a_dst    = a_src + (size_t)N * 8;               // N*8
    int*   deg      = (int*)(a_dst + (size_t)N * 8);       // N
    int*   off      = deg + N;                             // N+1
    int*   rank     = off + N + 1;                         // E
    int*   chunkSum = rank + E;                            // nChunks
    int*   chunkBase= chunkSum + nChunks;                  // nChunks
    int*   esrc     = chunkBase + nChunks;                 // E

    const int* e_src = ei;
    const int* e_dst = ei + E;

    hipMemsetAsync(deg, 0, (size_t)N * sizeof(int), stream);

    gat_linear_mfma<<<(N + 63) / 64, 256, 0, stream>>>(
        x, W, att_src, att_dst, h_bf, a_src, a_dst, N);

    int eb4 = (E / 4 + 256) / 256;
    gat_hist_rank<<<eb4, 256, 0, stream>>>(e_dst, deg, rank, E);
    gat_scan_chunks<<<nChunks, 256, 0, stream>>>(deg, off, chunkSum, N);
    gat_scan_tops<<<1, 128, 0, stream>>>(chunkSum, chunkBase, off, nChunks, N);
    gat_add_base<<<(N + 255) / 256, 256, 0, stream>>>(off, chunkBase, N);

    int nChunksE = (E + 1023) / 1024;
    gat_fill<<<nChunksE * 8, 256, 0, stream>>>(e_src, e_dst, rank, off, esrc, E, N);

    gat_gather<<<(N + 3) / 4, 256, 0, stream>>>(off, esrc, h_bf, a_src, a_dst, bias, out, N);
}

// Round 11
// 193.272 us; speedup vs baseline: 1.7503x; 1.0267x over previous
//
#include <hip/hip_runtime.h>
#include <cstdint>
#include <cstddef>

// GAT forward on MI355X — CSR-gather formulation.
// Round 11: (1) hist_rank FUSED with linear-MFMA in one kernel (role-split by
// blockIdx) — hist is atomic-latency-bound (VALUBusy 0.3%), linear is
// compute-bound; co-residency hides the hist stalls under MFMA work.
// (2) histogram split into 2 parity sub-arrays (deg0/deg1) to halve
// same-address atomic serialization; fill adds deg0[d] base for odd edges.

typedef __attribute__((ext_vector_type(8))) short short8v;  // 8 bf16 (4 VGPR)
typedef __attribute__((ext_vector_type(4))) float f32x4;    // acc (4 VGPR)

__device__ __forceinline__ unsigned short f2bf(float f) {
    unsigned u = __float_as_uint(f);
    unsigned r = u + 0x7FFFu + ((u >> 16) & 1u);   // round-to-nearest-even
    return (unsigned short)(r >> 16);
}
__device__ __forceinline__ float bf2f(unsigned short u) {
    return __uint_as_float(((unsigned)u) << 16);
}

// ---------------- Kernel 1: FUSED hist_rank | linear+logits (MFMA) --------
// Blocks [0, nHist): histogram+rank over edges (parity-split sub-arrays).
// Blocks [nHist, nHist+nLin): one 64x64 MFMA tile of h = x@W + fused logits.
__global__ __launch_bounds__(256) void gat_linear_hist(
    const float* __restrict__ x, const float* __restrict__ W,
    const float* __restrict__ att_src, const float* __restrict__ att_dst,
    unsigned short* __restrict__ h_bf, float* __restrict__ a_src,
    float* __restrict__ a_dst, const int* __restrict__ e_dst,
    int* __restrict__ deg0, int* __restrict__ deg1, int* __restrict__ rank,
    int N, int E, int nHist)
{
    __shared__ unsigned short Wt[64][136];   // linear role only
    const int tid = threadIdx.x;

    if ((int)blockIdx.x < nHist) {
        // ---- hist role: 1024 edges per block, int4 loads, parity sub-hist
        const int b = (int)blockIdx.x * 1024 + tid * 4;
        if (b + 3 < E) {
            int4 d = *reinterpret_cast<const int4*>(e_dst + b);
            int4 r;
            r.x = atomicAdd(&deg0[d.x], 1);   // even k -> sub0
            r.y = atomicAdd(&deg1[d.y], 1);   // odd  k -> sub1
            r.z = atomicAdd(&deg0[d.z], 1);
            r.w = atomicAdd(&deg1[d.w], 1);
            *reinterpret_cast<int4*>(rank + b) = r;
        } else {
            for (int k = b; k < E; ++k)
                rank[k] = atomicAdd(((k & 1) ? deg1 : deg0) + e_dst[k], 1);
        }
        return;
    }

    // ---- linear role
    const int lane = tid & 63;
    const int wi   = tid >> 6;

    for (int i = tid; i < 8192; i += 256) {
        const int k = i >> 6, col = i & 63;
        Wt[col][k] = f2bf(W[i]);
    }
    __syncthreads();

    const int r0   = ((int)blockIdx.x - nHist) * 64 + wi * 16;
    const int lrow = lane & 15;
    const int kgrp = (lane >> 4) * 8;
    const int row  = r0 + lrow;
    const int rowc = row < N ? row : N - 1;

    short8v bf[4][4];
    #pragma unroll
    for (int t = 0; t < 4; ++t)
        #pragma unroll
        for (int c = 0; c < 4; ++c)
            bf[t][c] = *reinterpret_cast<const short8v*>(&Wt[lrow + 16 * c][t * 32 + kgrp]);

    const float* xr = x + (size_t)rowc * 128 + kgrp;
    float4 xa[4][2];
    #pragma unroll
    for (int t = 0; t < 4; ++t) {
        xa[t][0] = *reinterpret_cast<const float4*>(xr + t * 32);
        xa[t][1] = *reinterpret_cast<const float4*>(xr + t * 32 + 4);
    }

    f32x4 acc[4] = {f32x4{0,0,0,0}, f32x4{0,0,0,0}, f32x4{0,0,0,0}, f32x4{0,0,0,0}};
    #pragma unroll
    for (int t = 0; t < 4; ++t) {
        short8v af;
        af[0] = (short)f2bf(xa[t][0].x); af[1] = (short)f2bf(xa[t][0].y);
        af[2] = (short)f2bf(xa[t][0].z); af[3] = (short)f2bf(xa[t][0].w);
        af[4] = (short)f2bf(xa[t][1].x); af[5] = (short)f2bf(xa[t][1].y);
        af[6] = (short)f2bf(xa[t][1].z); af[7] = (short)f2bf(xa[t][1].w);
        #pragma unroll
        for (int c = 0; c < 4; ++c)
            acc[c] = __builtin_amdgcn_mfma_f32_16x16x32_bf16(af, bf[t][c], acc[c], 0, 0, 0);
    }

    const int g = lane >> 4;
    float attS[4], attD[4];
    #pragma unroll
    for (int c = 0; c < 4; ++c) {
        attS[c] = att_src[lrow + 16 * c];
        attD[c] = att_dst[lrow + 16 * c];
    }

    #pragma unroll
    for (int reg = 0; reg < 4; ++reg) {
        const int r = r0 + g * 4 + reg;
        if (r < N) {   // uniform within each 16-lane group -> shfl-safe
            #pragma unroll
            for (int c = 0; c < 4; ++c) {
                const float v = acc[c][reg];
                h_bf[(size_t)r * 64 + lrow + 16 * c] = f2bf(v);
                float vs = v * attS[c];
                float vd = v * attD[c];
                vs += __shfl_xor(vs, 1, 64); vd += __shfl_xor(vd, 1, 64);
                vs += __shfl_xor(vs, 2, 64); vd += __shfl_xor(vd, 2, 64);
                vs += __shfl_xor(vs, 4, 64); vd += __shfl_xor(vd, 4, 64);
                if ((lane & 7) == 0) {
                    const int head = ((lane & 8) >> 3) + 2 * c;
                    a_src[r * 8 + head] = vs;
                    a_dst[r * 8 + head] = vd;
                }
            }
        }
    }
}

// ---------------- CSR scan ----------------
// Per-chunk (1024 nodes) exclusive scan of deg0+deg1; chunkSum[b] = total.
__global__ __launch_bounds__(256) void gat_scan_chunks(
    const int* __restrict__ deg0, const int* __restrict__ deg1,
    int* __restrict__ off, int* __restrict__ chunkSum, int N)
{
    __shared__ int lds[256];
    const int t = threadIdx.x;
    const int base = blockIdx.x * 1024 + t * 4;
    int v0 = 0, v1 = 0, v2 = 0, v3 = 0;
    if (base + 0 < N) v0 = deg0[base + 0] + deg1[base + 0];
    if (base + 1 < N) v1 = deg0[base + 1] + deg1[base + 1];
    if (base + 2 < N) v2 = deg0[base + 2] + deg1[base + 2];
    if (base + 3 < N) v3 = deg0[base + 3] + deg1[base + 3];
    int s = v0 + v1 + v2 + v3;
    lds[t] = s;
    __syncthreads();
    #pragma unroll
    for (int d = 1; d < 256; d <<= 1) {
        int add = (t >= d) ? lds[t - d] : 0;
        __syncthreads();
        lds[t] += add;
        __syncthreads();
    }
    if (t == 255) chunkSum[blockIdx.x] = lds[255];
    int p = lds[t] - s;  // exclusive within chunk
    if (base + 0 < N) off[base + 0] = p; p += v0;
    if (base + 1 < N) off[base + 1] = p; p += v1;
    if (base + 2 < N) off[base + 2] = p; p += v2;
    if (base + 3 < N) off[base + 3] = p;
}

// Exclusive scan of chunk sums (nChunks <= 128) in one 128-thread block.
__global__ __launch_bounds__(128) void gat_scan_tops(
    const int* __restrict__ chunkSum, int* __restrict__ chunkBase,
    int* __restrict__ off, int nChunks, int N)
{
    __shared__ int lds[128];
    const int t = threadIdx.x;
    if (nChunks > 128) {               // safety fallback (not hit at N=100k)
        if (t == 0) {
            int run = 0;
            for (int i = 0; i < nChunks; ++i) { chunkBase[i] = run; run += chunkSum[i]; }
            off[N] = run;
        }
        return;
    }
    int v = (t < nChunks) ? chunkSum[t] : 0;
    lds[t] = v;
    __syncthreads();
    #pragma unroll
    for (int d = 1; d < 128; d <<= 1) {
        int add = (t >= d) ? lds[t - d] : 0;
        __syncthreads();
        lds[t] += add;
        __syncthreads();
    }
    if (t < nChunks) chunkBase[t] = lds[t] - v;
    if (t == nChunks - 1) off[N] = lds[t];
}

__global__ __launch_bounds__(256) void gat_add_base(
    int* __restrict__ off, const int* __restrict__ chunkBase, int N)
{
    int i = blockIdx.x * 256 + threadIdx.x;
    if (i < N) off[i] += chunkBase[i >> 10];
}

// dst-range-partitioned, ATOMIC-FREE fill.
// Even edge k: pos = off[d] + rank[k] (sub0 slots first).
// Odd  edge k: pos = off[d] + deg0[d] + rank[k].
__global__ __launch_bounds__(256) void gat_fill(
    const int* __restrict__ e_src, const int* __restrict__ e_dst,
    const int* __restrict__ rank, const int* __restrict__ off,
    const int* __restrict__ deg0, int* __restrict__ esrc, int E, int N)
{
    const int range = blockIdx.x & 7;
    const int chunk = blockIdx.x >> 3;
    const int lo = (int)(((long long)N * range) >> 3);
    const int hi = (int)(((long long)N * (range + 1)) >> 3);

    const int b = chunk * 1024 + threadIdx.x * 4;
    if (b + 3 < E) {
        int4 sv = *reinterpret_cast<const int4*>(e_src + b);
        int4 dv = *reinterpret_cast<const int4*>(e_dst + b);
        int4 rv = *reinterpret_cast<const int4*>(rank + b);
        if (dv.x >= lo && dv.x < hi) esrc[off[dv.x] + rv.x] = sv.x;
        if (dv.y >= lo && dv.y < hi) esrc[off[dv.y] + deg0[dv.y] + rv.y] = sv.y;
        if (dv.z >= lo && dv.z < hi) esrc[off[dv.z] + rv.z] = sv.z;
        if (dv.w >= lo && dv.w < hi) esrc[off[dv.w] + deg0[dv.w] + rv.w] = sv.w;
    } else {
        for (int k = b; k < E; ++k) {
            int d = e_dst[k];
            if (d >= lo && d < hi)
                esrc[off[d] + ((k & 1) ? deg0[d] : 0) + rank[k]] = e_src[k];
        }
    }
}

// ---------------- Kernel 2: gather + softmax + ELU ----------------
// One wave per dst node; lane = head*8 + sub. Per 8-edge batch: lane reads
// esrc ONCE (edge k+sub), computes that edge's weight for its head, then
// both src index and weight are redistributed via shfl. h read as bf16.
__global__ __launch_bounds__(256) void gat_gather(
    const int* __restrict__ off, const int* __restrict__ esrc,
    const unsigned short* __restrict__ h_bf, const float* __restrict__ a_src,
    const float* __restrict__ a_dst, const float* __restrict__ bias,
    float* __restrict__ out, int N)
{
    const int node = blockIdx.x * 4 + (threadIdx.x >> 6);
    if (node >= N) return;
    const int lane = threadIdx.x & 63;
    const int head = lane >> 3;
    const int sub  = lane & 7;
    const int gbase = lane & 56;      // first lane of my head group

    const float ad = a_dst[node * 8 + head];
    // self-loop
    float e0 = a_src[node * 8 + head] + ad;
    e0 = e0 > 0.f ? e0 : 0.2f * e0;
    float w0 = __expf(e0);
    float acc = w0 * bf2f(h_bf[(uint32_t)node * 64u + (uint32_t)lane]);
    float s = w0;

    const int beg = off[node], end = off[node + 1];
    for (int k = beg; k < end; k += 8) {
        const int ke = k + sub;
        const int kc = ke < end ? ke : end - 1;
        const int sm = esrc[kc];
        float a = a_src[(uint32_t)sm * 8u + (uint32_t)head] + ad;
        a = a > 0.f ? a : 0.2f * a;
        const float wm = (ke < end) ? __expf(a) : 0.f;

        uint32_t hoff[8];
        #pragma unroll
        for (int u = 0; u < 8; ++u) {
            const int sb = __shfl(sm, gbase | u, 64);
            hoff[u] = (uint32_t)sb * 64u + (uint32_t)lane;
        }
        float hb[8];
        #pragma unroll
        for (int u = 0; u < 8; ++u) hb[u] = bf2f(h_bf[hoff[u]]);

        #pragma unroll
        for (int u = 0; u < 8; ++u) {
            const float w = __shfl(wm, gbase | u, 64);
            acc += w * hb[u];
            s += w;
        }
    }

    float v = acc / (s + 1e-16f) + bias[lane];
    out[(uint32_t)node * 64u + (uint32_t)lane] = v > 0.f ? v : expm1f(v);
}

extern "C" void kernel_launch(void* const* d_in, const int* in_sizes, int n_in,
                              void* d_out, int out_size, void* d_ws, size_t ws_size,
                              hipStream_t stream)
{
    const float* x       = (const float*)d_in[0];
    const float* W       = (const float*)d_in[1];
    const float* att_src = (const float*)d_in[2];
    const float* att_dst = (const float*)d_in[3];
    const float* bias    = (const float*)d_in[4];
    const int*   ei      = (const int*)d_in[5];   // int32 (JAX x64 disabled)

    const int N = in_sizes[0] / 128;
    const int E = in_sizes[5] / 2;
    const int nChunks = (N + 1023) / 1024;

    float* out = (float*)d_out;

    // workspace layout
    unsigned short* h_bf = (unsigned short*)d_ws;          // N*64 bf16
    float* a_src    = (float*)(h_bf + (size_t)N * 64);     // N*8 f32
    float* a_dst    = a_src + (size_t)N * 8;               // N*8
    int*   deg0     = (int*)(a_dst + (size_t)N * 8);       // N
    int*   deg1     = deg0 + N;                            // N
    int*   off      = deg1 + N;                            // N+1
    int*   rank     = off + N + 1;                         // E
    int*   chunkSum = rank + E;                            // nChunks
    int*   chunkBase= chunkSum + nChunks;                  // nChunks
    int*   esrc     = chunkBase + nChunks;                 // E

    const int* e_src = ei;
    const int* e_dst = ei + E;

    hipMemsetAsync(deg0, 0, (size_t)2 * N * sizeof(int), stream);

    const int nHist = (E + 1023) / 1024;
    const int nLin  = (N + 63) / 64;
    gat_linear_hist<<<nHist + nLin, 256, 0, stream>>>(
        x, W, att_src, att_dst, h_bf, a_src, a_dst,
        e_dst, deg0, deg1, rank, N, E, nHist);

    gat_scan_chunks<<<nChunks, 256, 0, stream>>>(deg0, deg1, off, chunkSum, N);
    gat_scan_tops<<<1, 128, 0, stream>>>(chunkSum, chunkBase, off, nChunks, N);
    gat_add_base<<<(N + 255) / 256, 256, 0, stream>>>(off, chunkBase, N);

    gat_fill<<<nHist * 8, 256, 0, stream>>>(e_src, e_dst, rank, off, deg0, esrc, E, N);

    gat_gather<<<(N + 3) / 4, 256, 0, stream>>>(off, esrc, h_bf, a_src, a_dst, bias, out, N);
}

// Round 12
// 183.525 us; speedup vs baseline: 1.8432x; 1.0531x over previous
//
#include <hip/hip_runtime.h>
#include <cstdint>
#include <cstddef>

// GAT forward on MI355X — CSR-gather formulation.
// Round 12: fused hist|linear kernel with BRESENHAM-INTERLEAVED roles so
// atomic-bound hist blocks and MFMA-bound linear blocks co-reside on every
// CU from t=0 (round 11 segregated them in dispatch order -> no overlap).
// Hist at 2 edges/thread (int2) to double atomic concurrency in flight.

typedef __attribute__((ext_vector_type(8))) short short8v;  // 8 bf16 (4 VGPR)
typedef __attribute__((ext_vector_type(4))) float f32x4;    // acc (4 VGPR)

__device__ __forceinline__ unsigned short f2bf(float f) {
    unsigned u = __float_as_uint(f);
    unsigned r = u + 0x7FFFu + ((u >> 16) & 1u);   // round-to-nearest-even
    return (unsigned short)(r >> 16);
}
__device__ __forceinline__ float bf2f(unsigned short u) {
    return __uint_as_float(((unsigned)u) << 16);
}

// ---------------- Kernel 1: FUSED hist_rank | linear+logits (MFMA) --------
// Role interleave: block b is a LINEAR block iff floor((b+1)*nLin/grid) >
// floor(b*nLin/grid)  (Bresenham; exactly nLin linear blocks, uniformly
// spread). lin_idx = floor(b*nLin/grid); hist_idx = b - lin_idx.
__global__ __launch_bounds__(256) void gat_linear_hist(
    const float* __restrict__ x, const float* __restrict__ W,
    const float* __restrict__ att_src, const float* __restrict__ att_dst,
    unsigned short* __restrict__ h_bf, float* __restrict__ a_src,
    float* __restrict__ a_dst, const int* __restrict__ e_dst,
    int* __restrict__ deg0, int* __restrict__ deg1, int* __restrict__ rank,
    int N, int E, int grid, int nLin)
{
    __shared__ unsigned short Wt[64][136];
    const int bid = (int)blockIdx.x;
    const int tid = threadIdx.x;
    const int L    = (int)(((long long)bid * nLin) / grid);
    const bool lin = (int)(((long long)(bid + 1) * nLin) / grid) > L;

    if (!lin) {
        // ---- hist role: 512 edges per block (2/thread, int2), parity split
        const int b = (bid - L) * 512 + tid * 2;
        if (b + 1 < E) {
            int2 d = *reinterpret_cast<const int2*>(e_dst + b);
            int2 r;
            r.x = atomicAdd(&deg0[d.x], 1);   // even k -> sub0
            r.y = atomicAdd(&deg1[d.y], 1);   // odd  k -> sub1
            *reinterpret_cast<int2*>(rank + b) = r;
        } else if (b < E) {
            rank[b] = atomicAdd(&deg0[e_dst[b]], 1);   // b is even
        }
        return;
    }

    // ---- linear role
    const int lane = tid & 63;
    const int wi   = tid >> 6;

    for (int i = tid; i < 8192; i += 256) {
        const int k = i >> 6, col = i & 63;
        Wt[col][k] = f2bf(W[i]);
    }
    __syncthreads();

    const int r0   = L * 64 + wi * 16;
    const int lrow = lane & 15;
    const int kgrp = (lane >> 4) * 8;
    const int row  = r0 + lrow;
    const int rowc = row < N ? row : N - 1;

    short8v bf[4][4];
    #pragma unroll
    for (int t = 0; t < 4; ++t)
        #pragma unroll
        for (int c = 0; c < 4; ++c)
            bf[t][c] = *reinterpret_cast<const short8v*>(&Wt[lrow + 16 * c][t * 32 + kgrp]);

    const float* xr = x + (size_t)rowc * 128 + kgrp;
    float4 xa[4][2];
    #pragma unroll
    for (int t = 0; t < 4; ++t) {
        xa[t][0] = *reinterpret_cast<const float4*>(xr + t * 32);
        xa[t][1] = *reinterpret_cast<const float4*>(xr + t * 32 + 4);
    }

    f32x4 acc[4] = {f32x4{0,0,0,0}, f32x4{0,0,0,0}, f32x4{0,0,0,0}, f32x4{0,0,0,0}};
    #pragma unroll
    for (int t = 0; t < 4; ++t) {
        short8v af;
        af[0] = (short)f2bf(xa[t][0].x); af[1] = (short)f2bf(xa[t][0].y);
        af[2] = (short)f2bf(xa[t][0].z); af[3] = (short)f2bf(xa[t][0].w);
        af[4] = (short)f2bf(xa[t][1].x); af[5] = (short)f2bf(xa[t][1].y);
        af[6] = (short)f2bf(xa[t][1].z); af[7] = (short)f2bf(xa[t][1].w);
        #pragma unroll
        for (int c = 0; c < 4; ++c)
            acc[c] = __builtin_amdgcn_mfma_f32_16x16x32_bf16(af, bf[t][c], acc[c], 0, 0, 0);
    }

    const int g = lane >> 4;
    float attS[4], attD[4];
    #pragma unroll
    for (int c = 0; c < 4; ++c) {
        attS[c] = att_src[lrow + 16 * c];
        attD[c] = att_dst[lrow + 16 * c];
    }

    #pragma unroll
    for (int reg = 0; reg < 4; ++reg) {
        const int r = r0 + g * 4 + reg;
        if (r < N) {   // uniform within each 16-lane group -> shfl-safe
            #pragma unroll
            for (int c = 0; c < 4; ++c) {
                const float v = acc[c][reg];
                h_bf[(size_t)r * 64 + lrow + 16 * c] = f2bf(v);
                float vs = v * attS[c];
                float vd = v * attD[c];
                vs += __shfl_xor(vs, 1, 64); vd += __shfl_xor(vd, 1, 64);
                vs += __shfl_xor(vs, 2, 64); vd += __shfl_xor(vd, 2, 64);
                vs += __shfl_xor(vs, 4, 64); vd += __shfl_xor(vd, 4, 64);
                if ((lane & 7) == 0) {
                    const int head = ((lane & 8) >> 3) + 2 * c;
                    a_src[r * 8 + head] = vs;
                    a_dst[r * 8 + head] = vd;
                }
            }
        }
    }
}

// ---------------- CSR scan ----------------
__global__ __launch_bounds__(256) void gat_scan_chunks(
    const int* __restrict__ deg0, const int* __restrict__ deg1,
    int* __restrict__ off, int* __restrict__ chunkSum, int N)
{
    __shared__ int lds[256];
    const int t = threadIdx.x;
    const int base = blockIdx.x * 1024 + t * 4;
    int v0 = 0, v1 = 0, v2 = 0, v3 = 0;
    if (base + 0 < N) v0 = deg0[base + 0] + deg1[base + 0];
    if (base + 1 < N) v1 = deg0[base + 1] + deg1[base + 1];
    if (base + 2 < N) v2 = deg0[base + 2] + deg1[base + 2];
    if (base + 3 < N) v3 = deg0[base + 3] + deg1[base + 3];
    int s = v0 + v1 + v2 + v3;
    lds[t] = s;
    __syncthreads();
    #pragma unroll
    for (int d = 1; d < 256; d <<= 1) {
        int add = (t >= d) ? lds[t - d] : 0;
        __syncthreads();
        lds[t] += add;
        __syncthreads();
    }
    if (t == 255) chunkSum[blockIdx.x] = lds[255];
    int p = lds[t] - s;  // exclusive within chunk
    if (base + 0 < N) off[base + 0] = p; p += v0;
    if (base + 1 < N) off[base + 1] = p; p += v1;
    if (base + 2 < N) off[base + 2] = p; p += v2;
    if (base + 3 < N) off[base + 3] = p;
}

__global__ __launch_bounds__(128) void gat_scan_tops(
    const int* __restrict__ chunkSum, int* __restrict__ chunkBase,
    int* __restrict__ off, int nChunks, int N)
{
    __shared__ int lds[128];
    const int t = threadIdx.x;
    if (nChunks > 128) {               // safety fallback (not hit at N=100k)
        if (t == 0) {
            int run = 0;
            for (int i = 0; i < nChunks; ++i) { chunkBase[i] = run; run += chunkSum[i]; }
            off[N] = run;
        }
        return;
    }
    int v = (t < nChunks) ? chunkSum[t] : 0;
    lds[t] = v;
    __syncthreads();
    #pragma unroll
    for (int d = 1; d < 128; d <<= 1) {
        int add = (t >= d) ? lds[t - d] : 0;
        __syncthreads();
        lds[t] += add;
        __syncthreads();
    }
    if (t < nChunks) chunkBase[t] = lds[t] - v;
    if (t == nChunks - 1) off[N] = lds[t];
}

__global__ __launch_bounds__(256) void gat_add_base(
    int* __restrict__ off, const int* __restrict__ chunkBase, int N)
{
    int i = blockIdx.x * 256 + threadIdx.x;
    if (i < N) off[i] += chunkBase[i >> 10];
}

// dst-range-partitioned, ATOMIC-FREE fill.
// Even edge k: pos = off[d] + rank[k]; odd: pos = off[d] + deg0[d] + rank[k].
__global__ __launch_bounds__(256) void gat_fill(
    const int* __restrict__ e_src, const int* __restrict__ e_dst,
    const int* __restrict__ rank, const int* __restrict__ off,
    const int* __restrict__ deg0, int* __restrict__ esrc, int E, int N)
{
    const int range = blockIdx.x & 7;
    const int chunk = blockIdx.x >> 3;
    const int lo = (int)(((long long)N * range) >> 3);
    const int hi = (int)(((long long)N * (range + 1)) >> 3);

    const int b = chunk * 1024 + threadIdx.x * 4;
    if (b + 3 < E) {
        int4 sv = *reinterpret_cast<const int4*>(e_src + b);
        int4 dv = *reinterpret_cast<const int4*>(e_dst + b);
        int4 rv = *reinterpret_cast<const int4*>(rank + b);
        if (dv.x >= lo && dv.x < hi) esrc[off[dv.x] + rv.x] = sv.x;
        if (dv.y >= lo && dv.y < hi) esrc[off[dv.y] + deg0[dv.y] + rv.y] = sv.y;
        if (dv.z >= lo && dv.z < hi) esrc[off[dv.z] + rv.z] = sv.z;
        if (dv.w >= lo && dv.w < hi) esrc[off[dv.w] + deg0[dv.w] + rv.w] = sv.w;
    } else {
        for (int k = b; k < E; ++k) {
            int d = e_dst[k];
            if (d >= lo && d < hi)
                esrc[off[d] + ((k & 1) ? deg0[d] : 0) + rank[k]] = e_src[k];
        }
    }
}

// ---------------- Kernel 2: gather + softmax + ELU ----------------
__global__ __launch_bounds__(256) void gat_gather(
    const int* __restrict__ off, const int* __restrict__ esrc,
    const unsigned short* __restrict__ h_bf, const float* __restrict__ a_src,
    const float* __restrict__ a_dst, const float* __restrict__ bias,
    float* __restrict__ out, int N)
{
    const int node = blockIdx.x * 4 + (threadIdx.x >> 6);
    if (node >= N) return;
    const int lane = threadIdx.x & 63;
    const int head = lane >> 3;
    const int sub  = lane & 7;
    const int gbase = lane & 56;      // first lane of my head group

    const float ad = a_dst[node * 8 + head];
    // self-loop
    float e0 = a_src[node * 8 + head] + ad;
    e0 = e0 > 0.f ? e0 : 0.2f * e0;
    float w0 = __expf(e0);
    float acc = w0 * bf2f(h_bf[(uint32_t)node * 64u + (uint32_t)lane]);
    float s = w0;

    const int beg = off[node], end = off[node + 1];
    for (int k = beg; k < end; k += 8) {
        const int ke = k + sub;
        const int kc = ke < end ? ke : end - 1;
        const int sm = esrc[kc];
        float a = a_src[(uint32_t)sm * 8u + (uint32_t)head] + ad;
        a = a > 0.f ? a : 0.2f * a;
        const float wm = (ke < end) ? __expf(a) : 0.f;

        uint32_t hoff[8];
        #pragma unroll
        for (int u = 0; u < 8; ++u) {
            const int sb = __shfl(sm, gbase | u, 64);
            hoff[u] = (uint32_t)sb * 64u + (uint32_t)lane;
        }
        float hb[8];
        #pragma unroll
        for (int u = 0; u < 8; ++u) hb[u] = bf2f(h_bf[hoff[u]]);

        #pragma unroll
        for (int u = 0; u < 8; ++u) {
            const float w = __shfl(wm, gbase | u, 64);
            acc += w * hb[u];
            s += w;
        }
    }

    float v = acc / (s + 1e-16f) + bias[lane];
    out[(uint32_t)node * 64u + (uint32_t)lane] = v > 0.f ? v : expm1f(v);
}

extern "C" void kernel_launch(void* const* d_in, const int* in_sizes, int n_in,
                              void* d_out, int out_size, void* d_ws, size_t ws_size,
                              hipStream_t stream)
{
    const float* x       = (const float*)d_in[0];
    const float* W       = (const float*)d_in[1];
    const float* att_src = (const float*)d_in[2];
    const float* att_dst = (const float*)d_in[3];
    const float* bias    = (const float*)d_in[4];
    const int*   ei      = (const int*)d_in[5];   // int32 (JAX x64 disabled)

    const int N = in_sizes[0] / 128;
    const int E = in_sizes[5] / 2;
    const int nChunks = (N + 1023) / 1024;

    float* out = (float*)d_out;

    // workspace layout
    unsigned short* h_bf = (unsigned short*)d_ws;          // N*64 bf16
    float* a_src    = (float*)(h_bf + (size_t)N * 64);     // N*8 f32
    float* a_dst    = a_src + (size_t)N * 8;               // N*8
    int*   deg0     = (int*)(a_dst + (size_t)N * 8);       // N
    int*   deg1     = deg0 + N;                            // N
    int*   off      = deg1 + N;                            // N+1
    int*   rank     = off + N + 1;                         // E
    int*   chunkSum = rank + E;                            // nChunks
    int*   chunkBase= chunkSum + nChunks;                  // nChunks
    int*   esrc     = chunkBase + nChunks;                 // E

    const int* e_src = ei;
    const int* e_dst = ei + E;

    hipMemsetAsync(deg0, 0, (size_t)2 * N * sizeof(int), stream);

    const int nHist = (E + 511) / 512;          // 512 edges per hist block
    const int nLin  = (N + 63) / 64;
    const int grid  = nHist + nLin;
    gat_linear_hist<<<grid, 256, 0, stream>>>(
        x, W, att_src, att_dst, h_bf, a_src, a_dst,
        e_dst, deg0, deg1, rank, N, E, grid, nLin);

    gat_scan_chunks<<<nChunks, 256, 0, stream>>>(deg0, deg1, off, chunkSum, N);
    gat_scan_tops<<<1, 128, 0, stream>>>(chunkSum, chunkBase, off, nChunks, N);
    gat_add_base<<<(N + 255) / 256, 256, 0, stream>>>(off, chunkBase, N);

    const int nChunksE = (E + 1023) / 1024;
    gat_fill<<<nChunksE * 8, 256, 0, stream>>>(e_src, e_dst, rank, off, deg0, esrc, E, N);

    gat_gather<<<(N + 3) / 4, 256, 0, stream>>>(off, esrc, h_bf, a_src, a_dst, bias, out, N);
}